// Round 12
// baseline (141.377 us; speedup 1.0000x reference)
//
#include <hip/hip_runtime.h>
#include <math.h>
#include <stdint.h>

#define B 32
#define NTOK 16384
#define DIM 64
#define NS 8
#define HID 128
#define BPB 32
#define JPB 512
#define NWAVE 4
#define JPW 128
#define CHUNKS 4
#define PARTF2 520              // l[8] + acc[8*64]
#define GRID (B*BPB)            // 1024
#define SCALE 0.125f
#define EPSA 1e-8f
#define LNEPS 1e-5f
#define SUMATTN (1.0f + (float)NTOK*EPSA)

typedef unsigned short ushort_t;
typedef __attribute__((ext_vector_type(8))) short bf16x8;
typedef __attribute__((ext_vector_type(4))) float f32x4;
typedef __attribute__((ext_vector_type(2))) unsigned int uint2v;

union U4H8 { uint4 u; bf16x8 h; };

__device__ __forceinline__ ushort_t f2bf(float f) {
  unsigned u = __float_as_uint(f);
  unsigned r = (u + 0x7fffu + ((u >> 16) & 1u)) >> 16;
  return (ushort_t)r;
}
__device__ __forceinline__ unsigned cvt_pk_bf16(float lo, float hi) {
  unsigned r;
  asm volatile("v_cvt_pk_bf16_f32 %0, %1, %2" : "=v"(r) : "v"(lo), "v"(hi));
  return r;
}
#define DS_TR(dst, addr, off) \
  asm volatile("ds_read_b64_tr_b16 %0, %1 offset:" #off : "=v"(dst) : "v"(addr))

// ---------------------------------------------------------------------------
// qp0_dev: per-block redundant qp/c from initial slots (verified R5-R11).
// ---------------------------------------------------------------------------
__device__ __forceinline__ void qp0_dev(
    const float* __restrict__ slots_b,
    const float* __restrict__ ln_s_g, const float* __restrict__ ln_s_b,
    const float* __restrict__ Wq, const float* __restrict__ bq,
    const float* __restrict__ Wk, const float* __restrict__ bk,
    ushort_t* sQp, float* sC, float* ovl, int t)
{
  float* sS = ovl;          // [8][64]
  float* sQ = ovl + 512;    // [8][64]
  if (t < NS) {
    const float* sr = slots_b + (size_t)t*DIM;
    float s1 = 0.f, s2 = 0.f;
    for (int d = 0; d < DIM; ++d) { float v = sr[d]; s1 += v; s2 += v*v; }
    float mu = s1*(1.0f/DIM);
    float var = s2*(1.0f/DIM) - mu*mu;
    float rs = rsqrtf(var + LNEPS);
    for (int d = 0; d < DIM; ++d) sS[t*DIM + d] = (sr[d]-mu)*rs*ln_s_g[d] + ln_s_b[d];
  }
  __syncthreads();
  for (int o = t; o < NS*DIM; o += 256) {
    int i = o >> 6, e = o & 63;
    float a = bq[e];
    const float* wr = Wq + e*DIM;
    for (int d = 0; d < DIM; ++d) a = fmaf(sS[i*DIM + d], wr[d], a);
    sQ[o] = a;
  }
  __syncthreads();
  for (int o = t; o < NS*DIM; o += 256) {
    int i = o >> 6, d = o & 63;
    float a = 0.f;
    for (int e = 0; e < DIM; ++e) a = fmaf(sQ[i*DIM + e], Wk[e*DIM + d], a);
    sQp[o] = f2bf(a*SCALE);
  }
  for (int o = t; o < NS*DIM; o += 256) sQp[512 + o] = 0;
  if (t < NS) {
    float a = 0.f;
    for (int e = 0; e < DIM; ++e) a = fmaf(sQ[t*DIM + e], bk[e], a);
    sC[t] = a*SCALE;
  }
  __syncthreads();
}

// ---------------------------------------------------------------------------
// flash_pass<FUSED,STORE>: verified MFMA flash core (R4-R11).
// STORE=1: packed bf16 exp(dots) into first half of strip's f32 region.
// ---------------------------------------------------------------------------
template<int FUSED, int STORE>
__device__ __forceinline__ void flash_pass(
    int bid, int t,
    const float* __restrict__ xf32, ushort_t* __restrict__ xlnb,
    const float* __restrict__ slots0,
    const ushort_t* __restrict__ qpg, const float* __restrict__ cbg,
    float* __restrict__ partials_out, float* __restrict__ xsp,
    float* __restrict__ dots_out,
    const float* __restrict__ ln_in_g, const float* __restrict__ ln_in_b,
    const float* __restrict__ ln_s_g, const float* __restrict__ ln_s_b,
    const float* __restrict__ Wq, const float* __restrict__ bq,
    const float* __restrict__ Wk, const float* __restrict__ bk,
    ushort_t (*lbuf)[2048], float (*sPart)[PARTF2], float (*sXs)[DIM],
    ushort_t* sQp, float* sC, float* ovl)
{
  const int b = bid >> 5, blk = bid & 31;
  const int w = t >> 6, lane = t & 63;
  const int c = lane & 15, g = lane >> 4;
  const int j0 = blk*JPB + w*JPW;

  const ushort_t* xb  = FUSED ? nullptr : (xlnb + ((size_t)b*NTOK + j0)*DIM);
  const float*    xfb = FUSED ? (xf32 + ((size_t)b*NTOK + j0)*DIM) : nullptr;
  ushort_t*       xob = FUSED ? (xlnb + ((size_t)b*NTOK + j0)*DIM) : nullptr;

  uint4 a00, a01, a10, a11;
  if (!FUSED) {
    a00 = *(const uint4*)(xb + c*DIM + g*8);
    a01 = *(const uint4*)(xb + c*DIM + g*8 + 32);
    a10 = *(const uint4*)(xb + (16 + c)*DIM + g*8);
    a11 = *(const uint4*)(xb + (16 + c)*DIM + g*8 + 32);
  }

  U4H8 bq0, bq1;
  float cb_l;
  if (FUSED) {
    qp0_dev(slots0 + (size_t)b*NS*DIM, ln_s_g, ln_s_b, Wq, bq, Wk, bk, sQp, sC, ovl, t);
    bq0.u = *(const uint4*)&sQp[c*DIM + g*8];
    bq1.u = *(const uint4*)&sQp[c*DIM + g*8 + 32];
    cb_l = (c < NS) ? sC[c] : 0.0f;
  } else {
    bq0.u = *(const uint4*)(qpg + (size_t)b*1024 + c*DIM + g*8);
    bq1.u = *(const uint4*)(qpg + (size_t)b*1024 + c*DIM + g*8 + 32);
    cb_l = (c < NS) ? cbg[b*NS + c] : 0.0f;
  }

  float gl[8], bl_[8], gh[8], bh[8], xs_lo[8], xs_hi[8];
  if (FUSED) {
    #pragma unroll
    for (int dd = 0; dd < 8; ++dd) {
      gl[dd] = ln_in_g[g*8 + dd];       bl_[dd] = ln_in_b[g*8 + dd];
      gh[dd] = ln_in_g[g*8 + 32 + dd];  bh[dd]  = ln_in_b[g*8 + 32 + dd];
      xs_lo[dd] = 0.f; xs_hi[dd] = 0.f;
    }
  }

  f32x4 acc0 = {0,0,0,0}, acc1 = {0,0,0,0}, acc2 = {0,0,0,0}, acc3 = {0,0,0,0};
  float lp = 0.0f;

  const unsigned lds0 = (unsigned)(uintptr_t)&lbuf[w][0];
  const unsigned trb = lds0 + (unsigned)(g*1024 + c*2);

  const int T0 = c, T1 = 16 + c;
  const int e00 = ((T0>>2)*4 + (g>>1)    )*64 + (T0&3)*16 + (g&1)*8;
  const int e01 = ((T0>>2)*4 + (g>>1) + 2)*64 + (T0&3)*16 + (g&1)*8;
  const int e10 = ((T1>>2)*4 + (g>>1)    )*64 + (T1&3)*16 + (g&1)*8;
  const int e11 = ((T1>>2)*4 + (g>>1) + 2)*64 + (T1&3)*16 + (g&1)*8;

  const int s0 = ((g & 1) << 5) + c;
  const bool til1 = (g >= 2);

  // strip-local packed bf16 destination: first half of this strip's region
  ushort_t* dseg = (STORE && c < NS)
      ? ((ushort_t*)(dots_out + ((size_t)(b*NS + c))*NTOK + (size_t)blk*JPB)) + w*JPW
      : nullptr;

  #pragma unroll
  for (int ch = 0; ch < CHUNKS; ++ch) {
    if (FUSED) {
      const float* xt = xfb + (size_t)ch*32*DIM;
      {
        const float* r = xt + T0*DIM + g*8;
        float4 q0 = *(const float4*)(r);
        float4 q1 = *(const float4*)(r + 4);
        float4 q2 = *(const float4*)(r + 32);
        float4 q3 = *(const float4*)(r + 36);
        float v[16] = {q0.x,q0.y,q0.z,q0.w, q1.x,q1.y,q1.z,q1.w,
                       q2.x,q2.y,q2.z,q2.w, q3.x,q3.y,q3.z,q3.w};
        float s1 = 0.f, s2 = 0.f;
        #pragma unroll
        for (int k = 0; k < 16; ++k) { s1 += v[k]; s2 = fmaf(v[k], v[k], s2); }
        s1 += __shfl_xor(s1, 16); s2 += __shfl_xor(s2, 16);
        s1 += __shfl_xor(s1, 32); s2 += __shfl_xor(s2, 32);
        float mu = s1*(1.0f/DIM);
        float var = s2*(1.0f/DIM) - mu*mu;
        float rs = rsqrtf(var + LNEPS);
        float xl[16];
        #pragma unroll
        for (int dd = 0; dd < 8; ++dd) {
          xl[dd]   = (v[dd]  -mu)*rs*gl[dd] + bl_[dd]; xs_lo[dd] += xl[dd];
          xl[8+dd] = (v[8+dd]-mu)*rs*gh[dd] + bh[dd];  xs_hi[dd] += xl[8+dd];
        }
        a00 = make_uint4(cvt_pk_bf16(xl[0],xl[1]),  cvt_pk_bf16(xl[2],xl[3]),
                         cvt_pk_bf16(xl[4],xl[5]),  cvt_pk_bf16(xl[6],xl[7]));
        a01 = make_uint4(cvt_pk_bf16(xl[8],xl[9]),  cvt_pk_bf16(xl[10],xl[11]),
                         cvt_pk_bf16(xl[12],xl[13]),cvt_pk_bf16(xl[14],xl[15]));
        *(uint4*)(xob + (size_t)(ch*32 + T0)*DIM + g*8)      = a00;
        *(uint4*)(xob + (size_t)(ch*32 + T0)*DIM + g*8 + 32) = a01;
      }
      {
        const float* r = xt + T1*DIM + g*8;
        float4 q0 = *(const float4*)(r);
        float4 q1 = *(const float4*)(r + 4);
        float4 q2 = *(const float4*)(r + 32);
        float4 q3 = *(const float4*)(r + 36);
        float v[16] = {q0.x,q0.y,q0.z,q0.w, q1.x,q1.y,q1.z,q1.w,
                       q2.x,q2.y,q2.z,q2.w, q3.x,q3.y,q3.z,q3.w};
        float s1 = 0.f, s2 = 0.f;
        #pragma unroll
        for (int k = 0; k < 16; ++k) { s1 += v[k]; s2 = fmaf(v[k], v[k], s2); }
        s1 += __shfl_xor(s1, 16); s2 += __shfl_xor(s2, 16);
        s1 += __shfl_xor(s1, 32); s2 += __shfl_xor(s2, 32);
        float mu = s1*(1.0f/DIM);
        float var = s2*(1.0f/DIM) - mu*mu;
        float rs = rsqrtf(var + LNEPS);
        float xl[16];
        #pragma unroll
        for (int dd = 0; dd < 8; ++dd) {
          xl[dd]   = (v[dd]  -mu)*rs*gl[dd] + bl_[dd]; xs_lo[dd] += xl[dd];
          xl[8+dd] = (v[8+dd]-mu)*rs*gh[dd] + bh[dd];  xs_hi[dd] += xl[8+dd];
        }
        a10 = make_uint4(cvt_pk_bf16(xl[0],xl[1]),  cvt_pk_bf16(xl[2],xl[3]),
                         cvt_pk_bf16(xl[4],xl[5]),  cvt_pk_bf16(xl[6],xl[7]));
        a11 = make_uint4(cvt_pk_bf16(xl[8],xl[9]),  cvt_pk_bf16(xl[10],xl[11]),
                         cvt_pk_bf16(xl[12],xl[13]),cvt_pk_bf16(xl[14],xl[15]));
        *(uint4*)(xob + (size_t)(ch*32 + T1)*DIM + g*8)      = a10;
        *(uint4*)(xob + (size_t)(ch*32 + T1)*DIM + g*8 + 32) = a11;
      }
    }

    *(uint4*)&lbuf[w][e00] = a00;
    *(uint4*)&lbuf[w][e01] = a01;
    *(uint4*)&lbuf[w][e10] = a10;
    *(uint4*)&lbuf[w][e11] = a11;

    uint4 n00, n01, n10, n11;
    if (!FUSED && ch + 1 < CHUNKS) {
      const ushort_t* xn = xb + (size_t)(ch + 1)*32*DIM;
      n00 = *(const uint4*)(xn + c*DIM + g*8);
      n01 = *(const uint4*)(xn + c*DIM + g*8 + 32);
      n10 = *(const uint4*)(xn + (16 + c)*DIM + g*8);
      n11 = *(const uint4*)(xn + (16 + c)*DIM + g*8 + 32);
    }

    f32x4 d0 = {0,0,0,0}, d1 = {0,0,0,0};
    { U4H8 A; A.u = a00; d0 = __builtin_amdgcn_mfma_f32_16x16x32_bf16(A.h, bq0.h, d0, 0,0,0); }
    { U4H8 A; A.u = a01; d0 = __builtin_amdgcn_mfma_f32_16x16x32_bf16(A.h, bq1.h, d0, 0,0,0); }
    { U4H8 A; A.u = a10; d1 = __builtin_amdgcn_mfma_f32_16x16x32_bf16(A.h, bq0.h, d1, 0,0,0); }
    { U4H8 A; A.u = a11; d1 = __builtin_amdgcn_mfma_f32_16x16x32_bf16(A.h, bq1.h, d1, 0,0,0); }

    float p00 = __expf(d0[0] + cb_l), p01 = __expf(d0[1] + cb_l);
    float p02 = __expf(d0[2] + cb_l), p03 = __expf(d0[3] + cb_l);
    float p10 = __expf(d1[0] + cb_l), p11 = __expf(d1[1] + cb_l);
    float p12 = __expf(d1[2] + cb_l), p13 = __expf(d1[3] + cb_l);
    lp += p00 + p01 + p02 + p03 + p10 + p11 + p12 + p13;

    unsigned pk00 = cvt_pk_bf16(p00, p01), pk01 = cvt_pk_bf16(p02, p03);
    unsigned pk10 = cvt_pk_bf16(p10, p11), pk11 = cvt_pk_bf16(p12, p13);

    if (STORE && c < NS) {
      *(uint2v*)(dseg + ch*32 + g*4)      = (uint2v){pk00, pk01};
      *(uint2v*)(dseg + ch*32 + 16 + g*4) = (uint2v){pk10, pk11};
    }

    unsigned b0a = (unsigned)__shfl((int)pk00, s0),      b0b = (unsigned)__shfl((int)pk10, s0);
    unsigned b1a = (unsigned)__shfl((int)pk01, s0),      b1b = (unsigned)__shfl((int)pk11, s0);
    unsigned b2a = (unsigned)__shfl((int)pk00, s0 + 16), b2b = (unsigned)__shfl((int)pk10, s0 + 16);
    unsigned b3a = (unsigned)__shfl((int)pk01, s0 + 16), b3b = (unsigned)__shfl((int)pk11, s0 + 16);
    U4H8 PB;
    PB.u = make_uint4(til1 ? b0b : b0a, til1 ? b1b : b1a,
                      til1 ? b2b : b2a, til1 ? b3b : b3a);

    asm volatile("s_waitcnt lgkmcnt(0)" ::: "memory");
    __builtin_amdgcn_sched_barrier(0);
    uint2v r0, r1, r2, r3, r4, r5, r6, r7;
    DS_TR(r0, trb, 0);   DS_TR(r1, trb, 512);
    DS_TR(r2, trb, 128); DS_TR(r3, trb, 640);
    DS_TR(r4, trb, 256); DS_TR(r5, trb, 768);
    DS_TR(r6, trb, 384); DS_TR(r7, trb, 896);
    asm volatile("s_waitcnt lgkmcnt(0)" ::: "memory");
    __builtin_amdgcn_sched_barrier(0);
    U4H8 X0, X1, X2, X3;
    X0.u = make_uint4(r0.x, r0.y, r1.x, r1.y);
    X1.u = make_uint4(r2.x, r2.y, r3.x, r3.y);
    X2.u = make_uint4(r4.x, r4.y, r5.x, r5.y);
    X3.u = make_uint4(r6.x, r6.y, r7.x, r7.y);
    acc0 = __builtin_amdgcn_mfma_f32_16x16x32_bf16(X0.h, PB.h, acc0, 0,0,0);
    acc1 = __builtin_amdgcn_mfma_f32_16x16x32_bf16(X1.h, PB.h, acc1, 0,0,0);
    acc2 = __builtin_amdgcn_mfma_f32_16x16x32_bf16(X2.h, PB.h, acc2, 0,0,0);
    acc3 = __builtin_amdgcn_mfma_f32_16x16x32_bf16(X3.h, PB.h, acc3, 0,0,0);

    if (!FUSED) { a00 = n00; a01 = n01; a10 = n10; a11 = n11; }
  }

  lp += __shfl_xor(lp, 16);
  lp += __shfl_xor(lp, 32);

  if (c < NS) {
    if (g == 0) sPart[w][c] = lp;
    #pragma unroll
    for (int r = 0; r < 4; ++r) sPart[w][8 + c*64 +  0 + g*4 + r] = acc0[r];
    #pragma unroll
    for (int r = 0; r < 4; ++r) sPart[w][8 + c*64 + 16 + g*4 + r] = acc1[r];
    #pragma unroll
    for (int r = 0; r < 4; ++r) sPart[w][8 + c*64 + 32 + g*4 + r] = acc2[r];
    #pragma unroll
    for (int r = 0; r < 4; ++r) sPart[w][8 + c*64 + 48 + g*4 + r] = acc3[r];
  }
  if (FUSED) {
    #pragma unroll
    for (int stepi = 0; stepi < 4; ++stepi) {
      const int mask = 1 << stepi;
      #pragma unroll
      for (int dd = 0; dd < 8; ++dd) {
        xs_lo[dd] += __shfl_xor(xs_lo[dd], mask);
        xs_hi[dd] += __shfl_xor(xs_hi[dd], mask);
      }
    }
    if (c == 0) {
      #pragma unroll
      for (int dd = 0; dd < 8; ++dd) {
        sXs[w][g*8 + dd]      = xs_lo[dd];
        sXs[w][g*8 + 32 + dd] = xs_hi[dd];
      }
    }
  }
  __syncthreads();
  float* P = partials_out + (size_t)bid * PARTF2;
  for (int o = t; o < PARTF2; o += 256)
    P[o] = sPart[0][o] + sPart[1][o] + sPart[2][o] + sPart[3][o];
  if (FUSED && t < DIM)
    xsp[(size_t)bid*DIM + t] = sXs[0][t] + sXs[1][t] + sXs[2][t] + sXs[3][t];
}

// ---------------------------------------------------------------------------
// update_slot: one (batch,slot) per 256-thread block (verified R6-R11).
// ---------------------------------------------------------------------------
__device__ __forceinline__ void update_slot(
    int bid, int t,
    const float* __restrict__ partials, const float* __restrict__ xsp,
    const float* __restrict__ prev_base, float* __restrict__ next_base,
    ushort_t* __restrict__ qp_next, float* __restrict__ cb_next,
    int do_qp,
    const float* __restrict__ ln_ff_g, const float* __restrict__ ln_ff_b,
    const float* __restrict__ ln_s_g, const float* __restrict__ ln_s_b,
    const float* __restrict__ Wq, const float* __restrict__ bq,
    const float* __restrict__ Wk, const float* __restrict__ bk,
    const float* __restrict__ Wv, const float* __restrict__ bv,
    const float* __restrict__ W_ih, const float* __restrict__ b_ih,
    const float* __restrict__ W_hh, const float* __restrict__ b_hh,
    const float* __restrict__ W1, const float* __restrict__ b1,
    const float* __restrict__ W2, const float* __restrict__ b2,
    float* ovl)
{
  const int bb = bid >> 3, i = bid & 7;
  const int q4 = t >> 6, d64 = t & 63;
  float* uUX  = ovl;        float* uUpd = ovl+64;   float* uPrev= ovl+128;
  float* uH   = ovl+192;    float* uHln = ovl+256;  float* uFin = ovl+320;
  float* uGx  = ovl+384;    float* uGh  = ovl+576;  float* uM1  = ovl+768;
  float* uS2  = ovl+896;    float* uQ2  = ovl+960;
  float* sRed = ovl+1024;   float* sRed2= ovl+1280;

  const float* Pb = partials + (size_t)bb*BPB*PARTF2;
  const float* xb = xsp + (size_t)bb*BPB*DIM;

  float a = 0.f, xa = 0.f;
  for (int p = q4; p < BPB; p += 4) {
    a  += Pb[p*PARTF2 + 8 + i*DIM + d64];
    xa += xb[p*DIM + d64];
  }
  sRed[q4*64+d64] = a; sRed2[q4*64+d64] = xa;
  if (t < DIM) uPrev[t] = prev_base[((size_t)bb*NS + i)*DIM + t];
  __syncthreads();
  if (t < DIM) {
    float lv = (t < BPB) ? Pb[t*PARTF2 + i] : 0.f;
    #pragma unroll
    for (int m = 1; m < 64; m <<= 1) lv += __shfl_xor(lv, m);
    float acc = sRed[t]+sRed[64+t]+sRed[128+t]+sRed[192+t];
    float xs  = sRed2[t]+sRed2[64+t]+sRed2[128+t]+sRed2[192+t];
    uUX[t] = acc/lv + EPSA*xs;
  }
  __syncthreads();
  {
    const float* wr = Wv + d64*DIM + q4*16;
    const float* ux = uUX + q4*16;
    float s = 0.f;
    #pragma unroll
    for (int d = 0; d < 16; ++d) s = fmaf(ux[d], wr[d], s);
    sRed[q4*64+d64] = s;
  }
  __syncthreads();
  if (t < DIM) uUpd[t] = bv[t]*SUMATTN + sRed[t]+sRed[64+t]+sRed[128+t]+sRed[192+t];
  __syncthreads();
  if (t < 3*DIM) {
    float ax = b_ih[t], ah = b_hh[t];
    const float* wx = W_ih + t*DIM;
    const float* wh = W_hh + t*DIM;
    for (int e = 0; e < DIM; ++e) {
      ax = fmaf(uUpd[e], wx[e], ax);
      ah = fmaf(uPrev[e], wh[e], ah);
    }
    uGx[t] = ax; uGh[t] = ah;
  }
  __syncthreads();
  if (t < DIM) {
    float r = 1.f/(1.f + __expf(-(uGx[t]+uGh[t])));
    float z = 1.f/(1.f + __expf(-(uGx[DIM+t]+uGh[DIM+t])));
    float n = tanhf(uGx[2*DIM+t] + r*uGh[2*DIM+t]);
    float h = (1.f - z)*n + z*uPrev[t];
    uH[t] = h;
    float s1 = h, s2v = h*h;
    #pragma unroll
    for (int m = 1; m < 64; m <<= 1) { s1 += __shfl_xor(s1,m); s2v += __shfl_xor(s2v,m); }
    float mu = s1*(1.f/DIM), var = s2v*(1.f/DIM) - mu*mu;
    float rs = rsqrtf(var + LNEPS);
    uHln[t] = (h - mu)*rs*ln_ff_g[t] + ln_ff_b[t];
  }
  __syncthreads();
  if (t < HID) {
    float s = b1[t];
    const float* wr = W1 + t*DIM;
    for (int d = 0; d < DIM; ++d) s = fmaf(uHln[d], wr[d], s);
    uM1[t] = fmaxf(s, 0.f);
  }
  __syncthreads();
  {
    const float* wr = W2 + d64*HID + q4*32;
    const float* mm = uM1 + q4*32;
    float s = 0.f;
    #pragma unroll
    for (int h = 0; h < 32; ++h) s = fmaf(mm[h], wr[h], s);
    sRed[q4*64+d64] = s;
  }
  __syncthreads();
  if (t < DIM) {
    float fin = uH[t] + b2[t] + sRed[t]+sRed[64+t]+sRed[128+t]+sRed[192+t];
    uFin[t] = fin;
    next_base[((size_t)bb*NS + i)*DIM + t] = fin;
  }
  if (do_qp) {
    __syncthreads();
    if (t < DIM) {
      float v = uFin[t];
      float s1 = v, s2v = v*v;
      #pragma unroll
      for (int m = 1; m < 64; m <<= 1) { s1 += __shfl_xor(s1,m); s2v += __shfl_xor(s2v,m); }
      float mu = s1*(1.f/DIM), var = s2v*(1.f/DIM) - mu*mu;
      float rs = rsqrtf(var + LNEPS);
      uS2[t] = (v - mu)*rs*ln_s_g[t] + ln_s_b[t];
    }
    __syncthreads();
    if (t < DIM) {
      float s = bq[t];
      const float* wr = Wq + t*DIM;
      for (int d = 0; d < DIM; ++d) s = fmaf(uS2[d], wr[d], s);
      uQ2[t] = s;
    }
    __syncthreads();
    if (t < DIM) {
      float s = 0.f;
      for (int e = 0; e < DIM; ++e) s = fmaf(uQ2[e], Wk[e*DIM + t], s);
      qp_next[(size_t)bb*1024 + i*DIM + t] = f2bf(s*SCALE);
      float cv = uQ2[t]*bk[t];
      #pragma unroll
      for (int m = 1; m < 64; m <<= 1) cv += __shfl_xor(cv, m);
      if (t == 0) cb_next[bb*NS + i] = cv*SCALE;
    }
    if (i == 0)
      for (int o = t; o < 512; o += 256) qp_next[(size_t)bb*1024 + 512 + o] = 0;
  }
}

#define SHARED_DECLS \
  __shared__ ushort_t lbuf[NWAVE][2048]; \
  __shared__ float sPart[NWAVE][PARTF2]; \
  __shared__ float sXs[NWAVE][DIM]; \
  __shared__ ushort_t sQp[16*DIM]; \
  __shared__ float sC[NS]; \
  float* ovl = (float*)&lbuf[0][0];

// Fused pass keeps default VGPR budget (high pressure from LN state).
__global__ __launch_bounds__(256) void g_flash_fused(
    const float* __restrict__ x, ushort_t* __restrict__ xlnb,
    const float* __restrict__ slots0,
    float* __restrict__ partials_out, float* __restrict__ xsp,
    const float* __restrict__ ln_in_g, const float* __restrict__ ln_in_b,
    const float* __restrict__ ln_s_g, const float* __restrict__ ln_s_b,
    const float* __restrict__ Wq, const float* __restrict__ bq,
    const float* __restrict__ Wk, const float* __restrict__ bk)
{
  SHARED_DECLS
  flash_pass<1,0>(blockIdx.x, threadIdx.x, x, xlnb, slots0, nullptr, nullptr,
      partials_out, xsp, nullptr, ln_in_g, ln_in_b, ln_s_g, ln_s_b,
      Wq, bq, Wk, bk, lbuf, sPart, sXs, sQp, sC, ovl);
}

// Non-fused passes: cap VGPR at 102 (5 waves/SIMD) for +25% occupancy.
template<int STORE>
__global__ __launch_bounds__(256, 5) void g_flash_iter(
    ushort_t* __restrict__ xlnb,
    const ushort_t* __restrict__ qpg, const float* __restrict__ cbg,
    float* __restrict__ partials_out, float* __restrict__ dots_out,
    const float* __restrict__ ln_in_g, const float* __restrict__ ln_in_b,
    const float* __restrict__ ln_s_g, const float* __restrict__ ln_s_b,
    const float* __restrict__ Wq, const float* __restrict__ bq,
    const float* __restrict__ Wk, const float* __restrict__ bk)
{
  SHARED_DECLS
  flash_pass<0,STORE>(blockIdx.x, threadIdx.x, nullptr, xlnb, nullptr, qpg, cbg,
      partials_out, nullptr, dots_out, ln_in_g, ln_in_b, ln_s_g, ln_s_b,
      Wq, bq, Wk, bk, lbuf, sPart, sXs, sQp, sC, ovl);
}

__global__ __launch_bounds__(256) void g_update(
    const float* __restrict__ partials, const float* __restrict__ xsp,
    const float* __restrict__ prev_base, float* __restrict__ next_base,
    ushort_t* __restrict__ qp_next, float* __restrict__ cb_next,
    const float* __restrict__ ln_ff_g, const float* __restrict__ ln_ff_b,
    const float* __restrict__ ln_s_g, const float* __restrict__ ln_s_b,
    const float* __restrict__ Wq, const float* __restrict__ bq,
    const float* __restrict__ Wk, const float* __restrict__ bk,
    const float* __restrict__ Wv, const float* __restrict__ bv,
    const float* __restrict__ W_ih, const float* __restrict__ b_ih,
    const float* __restrict__ W_hh, const float* __restrict__ b_hh,
    const float* __restrict__ W1, const float* __restrict__ b1,
    const float* __restrict__ W2, const float* __restrict__ b2)
{
  __shared__ float ovl2[1600];
  update_slot(blockIdx.x, threadIdx.x, partials, xsp, prev_base, next_base,
              qp_next, cb_next, 1,
              ln_ff_g, ln_ff_b, ln_s_g, ln_s_b, Wq, bq, Wk, bk, Wv, bv,
              W_ih, b_ih, W_hh, b_hh, W1, b1, W2, b2, ovl2);
}

// ---------------------------------------------------------------------------
// k_fin: per-block 1/l; stage strip's packed bf16 exp-dots into LDS, expand
// to f32 scaled attn in place; blk<8 blocks do final slot update -> outslots.
// ---------------------------------------------------------------------------
__global__ __launch_bounds__(256) void k_fin(
    const float* __restrict__ partials, const float* __restrict__ xsp,
    const float* __restrict__ prev_base,
    float* __restrict__ out, float* __restrict__ outslots,
    const float* __restrict__ ln_ff_g, const float* __restrict__ ln_ff_b,
    const float* __restrict__ ln_s_g, const float* __restrict__ ln_s_b,
    const float* __restrict__ Wq, const float* __restrict__ bq,
    const float* __restrict__ Wk, const float* __restrict__ bk,
    const float* __restrict__ Wv, const float* __restrict__ bv,
    const float* __restrict__ W_ih, const float* __restrict__ b_ih,
    const float* __restrict__ W_hh, const float* __restrict__ b_hh,
    const float* __restrict__ W1, const float* __restrict__ b1,
    const float* __restrict__ W2, const float* __restrict__ b2)
{
  __shared__ float ovl2[1600];
  __shared__ float sLi[NS];
  __shared__ ushort_t sPk[NS*JPB];   // 8 rows x 512 packed bf16 (8 KB)
  const int bid = blockIdx.x, t = threadIdx.x;
  const int b = bid >> 5, blk = bid & 31;
  const float* Pb = partials + (size_t)b*BPB*PARTF2;

  if (t < NS) {
    float ll = 0.f;
    for (int p = 0; p < BPB; ++p) ll += Pb[p*PARTF2 + t];
    sLi[t] = 1.0f/ll;
  }
  for (int idx = t; idx < NS*JPB/4; idx += 256) {
    int r = idx >> 7, q = idx & 127;
    const ushort_t* seg = (const ushort_t*)(out + ((size_t)(b*NS + r))*NTOK + (size_t)blk*JPB);
    *(uint2v*)&sPk[r*JPB + q*4] = *(const uint2v*)(seg + q*4);
  }
  __syncthreads();
  for (int idx = t; idx < 1024; idx += 256) {
    int r = idx >> 7, c4 = idx & 127;
    const ushort_t* pk = &sPk[r*JPB + c4*4];
    float li = sLi[r];
    float4 v;
    v.x = __uint_as_float((unsigned)pk[0] << 16)*li + EPSA;
    v.y = __uint_as_float((unsigned)pk[1] << 16)*li + EPSA;
    v.z = __uint_as_float((unsigned)pk[2] << 16)*li + EPSA;
    v.w = __uint_as_float((unsigned)pk[3] << 16)*li + EPSA;
    *((float4*)out + ((size_t)(b*NS + r))*(NTOK/4) + blk*(JPB/4) + c4) = v;
  }
  if (blk < NS) {
    update_slot(b*NS + blk, t, partials, xsp, prev_base, outslots,
                nullptr, nullptr, 0,
                ln_ff_g, ln_ff_b, ln_s_g, ln_s_b, Wq, bq, Wk, bk, Wv, bv,
                W_ih, b_ih, W_hh, b_hh, W1, b1, W2, b2, ovl2);
  }
}

extern "C" void kernel_launch(void* const* d_in, const int* in_sizes, int n_in,
                              void* d_out, int out_size, void* d_ws, size_t ws_size,
                              hipStream_t stream)
{
  const float* x       = (const float*)d_in[0];
  const float* slots0  = (const float*)d_in[1];
  const float* ln_in_g = (const float*)d_in[2];
  const float* ln_in_b = (const float*)d_in[3];
  const float* ln_s_g  = (const float*)d_in[4];
  const float* ln_s_b  = (const float*)d_in[5];
  const float* ln_ff_g = (const float*)d_in[6];
  const float* ln_ff_b = (const float*)d_in[7];
  const float* Wq = (const float*)d_in[8];
  const float* bq = (const float*)d_in[9];
  const float* Wk = (const float*)d_in[10];
  const float* bk = (const float*)d_in[11];
  const float* Wv = (const float*)d_in[12];
  const float* bv = (const float*)d_in[13];
  const float* W_ih = (const float*)d_in[14];
  const float* b_ih = (const float*)d_in[15];
  const float* W_hh = (const float*)d_in[16];
  const float* b_hh = (const float*)d_in[17];
  const float* W1 = (const float*)d_in[18];
  const float* b1 = (const float*)d_in[19];
  const float* W2 = (const float*)d_in[20];
  const float* b2 = (const float*)d_in[21];

  float* out = (float*)d_out;
  float* outslots = out + (size_t)B*NS*NTOK;

  float* pA   = (float*)d_ws;                          // 1024*520
  float* xsp  = pA + (size_t)GRID*PARTF2;              // 1024*64
  float* cb1  = xsp + (size_t)GRID*DIM;                // 256
  float* cb2  = cb1 + B*NS;                            // 256
  float* s1v  = cb2 + B*NS;                            // 16384
  float* s2v  = s1v + (size_t)B*NS*DIM;                // 16384
  ushort_t* qp1 = (ushort_t*)(s2v + (size_t)B*NS*DIM); // 32*1024 bf16
  ushort_t* qp2 = qp1 + (size_t)B*1024;                // 32*1024 bf16
  ushort_t* xlnb = qp2 + (size_t)B*1024;               // 32*16384*64 bf16

  dim3 gF(GRID), gU(B*NS), blk(256);

  // iter 0: qp0 preamble + fused LN flash (writes xln, xsp, pA)
  g_flash_fused<<<gF, blk, 0, stream>>>(x, xlnb, slots0, pA, xsp,
      ln_in_g, ln_in_b, ln_s_g, ln_s_b, Wq, bq, Wk, bk);
  // update 0 -> slots1 + qp1
  g_update<<<gU, blk, 0, stream>>>(pA, xsp, slots0, s1v, qp1, cb1,
      ln_ff_g, ln_ff_b, ln_s_g, ln_s_b, Wq, bq, Wk, bk, Wv, bv,
      W_ih, b_ih, W_hh, b_hh, W1, b1, W2, b2);
  // iter 1 flash
  g_flash_iter<0><<<gF, blk, 0, stream>>>(xlnb, qp1, cb1, pA, nullptr,
      ln_in_g, ln_in_b, ln_s_g, ln_s_b, Wq, bq, Wk, bk);
  // update 1 -> slots2 + qp2
  g_update<<<gU, blk, 0, stream>>>(pA, xsp, s1v, s2v, qp2, cb2,
      ln_ff_g, ln_ff_b, ln_s_g, ln_s_b, Wq, bq, Wk, bk, Wv, bv,
      W_ih, b_ih, W_hh, b_hh, W1, b1, W2, b2);
  // iter 2 flash: store packed bf16 exp(dots) strip-locally into attn region
  g_flash_iter<1><<<gF, blk, 0, stream>>>(xlnb, qp2, cb2, pA, out,
      ln_in_g, ln_in_b, ln_s_g, ln_s_b, Wq, bq, Wk, bk);
  // finalize: expand bf16 -> scaled f32 attn (write once); blk<8 final update
  k_fin<<<gF, blk, 0, stream>>>(pA, xsp, s2v, out, outslots,
      ln_ff_g, ln_ff_b, ln_s_g, ln_s_b, Wq, bq, Wk, bk, Wv, bv,
      W_ih, b_ih, W_hh, b_hh, W1, b1, W2, b2);
}

// Round 13
// 138.205 us; speedup vs baseline: 1.0229x; 1.0229x over previous
//
#include <hip/hip_runtime.h>
#include <math.h>
#include <stdint.h>

#define B 32
#define NTOK 16384
#define DIM 64
#define NS 8
#define HID 128
#define BPB 32
#define JPB 512
#define NWAVE 4
#define JPW 128
#define CHUNKS 4
#define PARTF2 520              // l[8] + acc[8*64]
#define GRID (B*BPB)            // 1024
#define SCALE 0.125f
#define EPSA 1e-8f
#define LNEPS 1e-5f
#define SUMATTN (1.0f + (float)NTOK*EPSA)

typedef unsigned short ushort_t;
typedef __attribute__((ext_vector_type(8))) short bf16x8;
typedef __attribute__((ext_vector_type(4))) float f32x4;
typedef __attribute__((ext_vector_type(2))) unsigned int uint2v;

union U4H8 { uint4 u; bf16x8 h; };

__device__ __forceinline__ ushort_t f2bf(float f) {
  unsigned u = __float_as_uint(f);
  unsigned r = (u + 0x7fffu + ((u >> 16) & 1u)) >> 16;
  return (ushort_t)r;
}
__device__ __forceinline__ unsigned cvt_pk_bf16(float lo, float hi) {
  unsigned r;
  asm volatile("v_cvt_pk_bf16_f32 %0, %1, %2" : "=v"(r) : "v"(lo), "v"(hi));
  return r;
}
#define DS_TR(dst, addr, off) \
  asm volatile("ds_read_b64_tr_b16 %0, %1 offset:" #off : "=v"(dst) : "v"(addr))

// ---------------------------------------------------------------------------
// qp0_dev: per-block redundant qp/c from initial slots (verified R5-R11).
// ---------------------------------------------------------------------------
__device__ __forceinline__ void qp0_dev(
    const float* __restrict__ slots_b,
    const float* __restrict__ ln_s_g, const float* __restrict__ ln_s_b,
    const float* __restrict__ Wq, const float* __restrict__ bq,
    const float* __restrict__ Wk, const float* __restrict__ bk,
    ushort_t* sQp, float* sC, float* ovl, int t)
{
  float* sS = ovl;          // [8][64]
  float* sQ = ovl + 512;    // [8][64]
  if (t < NS) {
    const float* sr = slots_b + (size_t)t*DIM;
    float s1 = 0.f, s2 = 0.f;
    for (int d = 0; d < DIM; ++d) { float v = sr[d]; s1 += v; s2 += v*v; }
    float mu = s1*(1.0f/DIM);
    float var = s2*(1.0f/DIM) - mu*mu;
    float rs = rsqrtf(var + LNEPS);
    for (int d = 0; d < DIM; ++d) sS[t*DIM + d] = (sr[d]-mu)*rs*ln_s_g[d] + ln_s_b[d];
  }
  __syncthreads();
  for (int o = t; o < NS*DIM; o += 256) {
    int i = o >> 6, e = o & 63;
    float a = bq[e];
    const float* wr = Wq + e*DIM;
    for (int d = 0; d < DIM; ++d) a = fmaf(sS[i*DIM + d], wr[d], a);
    sQ[o] = a;
  }
  __syncthreads();
  for (int o = t; o < NS*DIM; o += 256) {
    int i = o >> 6, d = o & 63;
    float a = 0.f;
    for (int e = 0; e < DIM; ++e) a = fmaf(sQ[i*DIM + e], Wk[e*DIM + d], a);
    sQp[o] = f2bf(a*SCALE);
  }
  for (int o = t; o < NS*DIM; o += 256) sQp[512 + o] = 0;
  if (t < NS) {
    float a = 0.f;
    for (int e = 0; e < DIM; ++e) a = fmaf(sQ[t*DIM + e], bk[e], a);
    sC[t] = a*SCALE;
  }
  __syncthreads();
}

// ---------------------------------------------------------------------------
// flash_pass<FUSED,STORE>: verified MFMA flash core (R4-R11).
// STORE=1: packed bf16 exp(dots) into first half of strip's f32 region.
// ---------------------------------------------------------------------------
template<int FUSED, int STORE>
__device__ __forceinline__ void flash_pass(
    int bid, int t,
    const float* __restrict__ xf32, ushort_t* __restrict__ xlnb,
    const float* __restrict__ slots0,
    const ushort_t* __restrict__ qpg, const float* __restrict__ cbg,
    float* __restrict__ partials_out, float* __restrict__ xsp,
    float* __restrict__ dots_out,
    const float* __restrict__ ln_in_g, const float* __restrict__ ln_in_b,
    const float* __restrict__ ln_s_g, const float* __restrict__ ln_s_b,
    const float* __restrict__ Wq, const float* __restrict__ bq,
    const float* __restrict__ Wk, const float* __restrict__ bk,
    ushort_t (*lbuf)[2048], float (*sPart)[PARTF2], float (*sXs)[DIM],
    ushort_t* sQp, float* sC, float* ovl)
{
  const int b = bid >> 5, blk = bid & 31;
  const int w = t >> 6, lane = t & 63;
  const int c = lane & 15, g = lane >> 4;
  const int j0 = blk*JPB + w*JPW;

  const ushort_t* xb  = FUSED ? nullptr : (xlnb + ((size_t)b*NTOK + j0)*DIM);
  const float*    xfb = FUSED ? (xf32 + ((size_t)b*NTOK + j0)*DIM) : nullptr;
  ushort_t*       xob = FUSED ? (xlnb + ((size_t)b*NTOK + j0)*DIM) : nullptr;

  uint4 a00, a01, a10, a11;
  if (!FUSED) {
    a00 = *(const uint4*)(xb + c*DIM + g*8);
    a01 = *(const uint4*)(xb + c*DIM + g*8 + 32);
    a10 = *(const uint4*)(xb + (16 + c)*DIM + g*8);
    a11 = *(const uint4*)(xb + (16 + c)*DIM + g*8 + 32);
  }

  U4H8 bq0, bq1;
  float cb_l;
  if (FUSED) {
    qp0_dev(slots0 + (size_t)b*NS*DIM, ln_s_g, ln_s_b, Wq, bq, Wk, bk, sQp, sC, ovl, t);
    bq0.u = *(const uint4*)&sQp[c*DIM + g*8];
    bq1.u = *(const uint4*)&sQp[c*DIM + g*8 + 32];
    cb_l = (c < NS) ? sC[c] : 0.0f;
  } else {
    bq0.u = *(const uint4*)(qpg + (size_t)b*1024 + c*DIM + g*8);
    bq1.u = *(const uint4*)(qpg + (size_t)b*1024 + c*DIM + g*8 + 32);
    cb_l = (c < NS) ? cbg[b*NS + c] : 0.0f;
  }

  float gl[8], bl_[8], gh[8], bh[8], xs_lo[8], xs_hi[8];
  if (FUSED) {
    #pragma unroll
    for (int dd = 0; dd < 8; ++dd) {
      gl[dd] = ln_in_g[g*8 + dd];       bl_[dd] = ln_in_b[g*8 + dd];
      gh[dd] = ln_in_g[g*8 + 32 + dd];  bh[dd]  = ln_in_b[g*8 + 32 + dd];
      xs_lo[dd] = 0.f; xs_hi[dd] = 0.f;
    }
  }

  f32x4 acc0 = {0,0,0,0}, acc1 = {0,0,0,0}, acc2 = {0,0,0,0}, acc3 = {0,0,0,0};
  float lp = 0.0f;

  const unsigned lds0 = (unsigned)(uintptr_t)&lbuf[w][0];
  const unsigned trb = lds0 + (unsigned)(g*1024 + c*2);

  const int T0 = c, T1 = 16 + c;
  const int e00 = ((T0>>2)*4 + (g>>1)    )*64 + (T0&3)*16 + (g&1)*8;
  const int e01 = ((T0>>2)*4 + (g>>1) + 2)*64 + (T0&3)*16 + (g&1)*8;
  const int e10 = ((T1>>2)*4 + (g>>1)    )*64 + (T1&3)*16 + (g&1)*8;
  const int e11 = ((T1>>2)*4 + (g>>1) + 2)*64 + (T1&3)*16 + (g&1)*8;

  const int s0 = ((g & 1) << 5) + c;
  const bool til1 = (g >= 2);

  // strip-local packed bf16 destination: first half of this strip's region
  ushort_t* dseg = (STORE && c < NS)
      ? ((ushort_t*)(dots_out + ((size_t)(b*NS + c))*NTOK + (size_t)blk*JPB)) + w*JPW
      : nullptr;

  #pragma unroll
  for (int ch = 0; ch < CHUNKS; ++ch) {
    if (FUSED) {
      const float* xt = xfb + (size_t)ch*32*DIM;
      {
        const float* r = xt + T0*DIM + g*8;
        float4 q0 = *(const float4*)(r);
        float4 q1 = *(const float4*)(r + 4);
        float4 q2 = *(const float4*)(r + 32);
        float4 q3 = *(const float4*)(r + 36);
        float v[16] = {q0.x,q0.y,q0.z,q0.w, q1.x,q1.y,q1.z,q1.w,
                       q2.x,q2.y,q2.z,q2.w, q3.x,q3.y,q3.z,q3.w};
        float s1 = 0.f, s2 = 0.f;
        #pragma unroll
        for (int k = 0; k < 16; ++k) { s1 += v[k]; s2 = fmaf(v[k], v[k], s2); }
        s1 += __shfl_xor(s1, 16); s2 += __shfl_xor(s2, 16);
        s1 += __shfl_xor(s1, 32); s2 += __shfl_xor(s2, 32);
        float mu = s1*(1.0f/DIM);
        float var = s2*(1.0f/DIM) - mu*mu;
        float rs = rsqrtf(var + LNEPS);
        float xl[16];
        #pragma unroll
        for (int dd = 0; dd < 8; ++dd) {
          xl[dd]   = (v[dd]  -mu)*rs*gl[dd] + bl_[dd]; xs_lo[dd] += xl[dd];
          xl[8+dd] = (v[8+dd]-mu)*rs*gh[dd] + bh[dd];  xs_hi[dd] += xl[8+dd];
        }
        a00 = make_uint4(cvt_pk_bf16(xl[0],xl[1]),  cvt_pk_bf16(xl[2],xl[3]),
                         cvt_pk_bf16(xl[4],xl[5]),  cvt_pk_bf16(xl[6],xl[7]));
        a01 = make_uint4(cvt_pk_bf16(xl[8],xl[9]),  cvt_pk_bf16(xl[10],xl[11]),
                         cvt_pk_bf16(xl[12],xl[13]),cvt_pk_bf16(xl[14],xl[15]));
        *(uint4*)(xob + (size_t)(ch*32 + T0)*DIM + g*8)      = a00;
        *(uint4*)(xob + (size_t)(ch*32 + T0)*DIM + g*8 + 32) = a01;
      }
      {
        const float* r = xt + T1*DIM + g*8;
        float4 q0 = *(const float4*)(r);
        float4 q1 = *(const float4*)(r + 4);
        float4 q2 = *(const float4*)(r + 32);
        float4 q3 = *(const float4*)(r + 36);
        float v[16] = {q0.x,q0.y,q0.z,q0.w, q1.x,q1.y,q1.z,q1.w,
                       q2.x,q2.y,q2.z,q2.w, q3.x,q3.y,q3.z,q3.w};
        float s1 = 0.f, s2 = 0.f;
        #pragma unroll
        for (int k = 0; k < 16; ++k) { s1 += v[k]; s2 = fmaf(v[k], v[k], s2); }
        s1 += __shfl_xor(s1, 16); s2 += __shfl_xor(s2, 16);
        s1 += __shfl_xor(s1, 32); s2 += __shfl_xor(s2, 32);
        float mu = s1*(1.0f/DIM);
        float var = s2*(1.0f/DIM) - mu*mu;
        float rs = rsqrtf(var + LNEPS);
        float xl[16];
        #pragma unroll
        for (int dd = 0; dd < 8; ++dd) {
          xl[dd]   = (v[dd]  -mu)*rs*gl[dd] + bl_[dd]; xs_lo[dd] += xl[dd];
          xl[8+dd] = (v[8+dd]-mu)*rs*gh[dd] + bh[dd];  xs_hi[dd] += xl[8+dd];
        }
        a10 = make_uint4(cvt_pk_bf16(xl[0],xl[1]),  cvt_pk_bf16(xl[2],xl[3]),
                         cvt_pk_bf16(xl[4],xl[5]),  cvt_pk_bf16(xl[6],xl[7]));
        a11 = make_uint4(cvt_pk_bf16(xl[8],xl[9]),  cvt_pk_bf16(xl[10],xl[11]),
                         cvt_pk_bf16(xl[12],xl[13]),cvt_pk_bf16(xl[14],xl[15]));
        *(uint4*)(xob + (size_t)(ch*32 + T1)*DIM + g*8)      = a10;
        *(uint4*)(xob + (size_t)(ch*32 + T1)*DIM + g*8 + 32) = a11;
      }
    }

    *(uint4*)&lbuf[w][e00] = a00;
    *(uint4*)&lbuf[w][e01] = a01;
    *(uint4*)&lbuf[w][e10] = a10;
    *(uint4*)&lbuf[w][e11] = a11;

    uint4 n00, n01, n10, n11;
    if (!FUSED && ch + 1 < CHUNKS) {
      const ushort_t* xn = xb + (size_t)(ch + 1)*32*DIM;
      n00 = *(const uint4*)(xn + c*DIM + g*8);
      n01 = *(const uint4*)(xn + c*DIM + g*8 + 32);
      n10 = *(const uint4*)(xn + (16 + c)*DIM + g*8);
      n11 = *(const uint4*)(xn + (16 + c)*DIM + g*8 + 32);
    }

    f32x4 d0 = {0,0,0,0}, d1 = {0,0,0,0};
    { U4H8 A; A.u = a00; d0 = __builtin_amdgcn_mfma_f32_16x16x32_bf16(A.h, bq0.h, d0, 0,0,0); }
    { U4H8 A; A.u = a01; d0 = __builtin_amdgcn_mfma_f32_16x16x32_bf16(A.h, bq1.h, d0, 0,0,0); }
    { U4H8 A; A.u = a10; d1 = __builtin_amdgcn_mfma_f32_16x16x32_bf16(A.h, bq0.h, d1, 0,0,0); }
    { U4H8 A; A.u = a11; d1 = __builtin_amdgcn_mfma_f32_16x16x32_bf16(A.h, bq1.h, d1, 0,0,0); }

    float p00 = __expf(d0[0] + cb_l), p01 = __expf(d0[1] + cb_l);
    float p02 = __expf(d0[2] + cb_l), p03 = __expf(d0[3] + cb_l);
    float p10 = __expf(d1[0] + cb_l), p11 = __expf(d1[1] + cb_l);
    float p12 = __expf(d1[2] + cb_l), p13 = __expf(d1[3] + cb_l);
    lp += p00 + p01 + p02 + p03 + p10 + p11 + p12 + p13;

    unsigned pk00 = cvt_pk_bf16(p00, p01), pk01 = cvt_pk_bf16(p02, p03);
    unsigned pk10 = cvt_pk_bf16(p10, p11), pk11 = cvt_pk_bf16(p12, p13);

    if (STORE && c < NS) {
      *(uint2v*)(dseg + ch*32 + g*4)      = (uint2v){pk00, pk01};
      *(uint2v*)(dseg + ch*32 + 16 + g*4) = (uint2v){pk10, pk11};
    }

    unsigned b0a = (unsigned)__shfl((int)pk00, s0),      b0b = (unsigned)__shfl((int)pk10, s0);
    unsigned b1a = (unsigned)__shfl((int)pk01, s0),      b1b = (unsigned)__shfl((int)pk11, s0);
    unsigned b2a = (unsigned)__shfl((int)pk00, s0 + 16), b2b = (unsigned)__shfl((int)pk10, s0 + 16);
    unsigned b3a = (unsigned)__shfl((int)pk01, s0 + 16), b3b = (unsigned)__shfl((int)pk11, s0 + 16);
    U4H8 PB;
    PB.u = make_uint4(til1 ? b0b : b0a, til1 ? b1b : b1a,
                      til1 ? b2b : b2a, til1 ? b3b : b3a);

    asm volatile("s_waitcnt lgkmcnt(0)" ::: "memory");
    __builtin_amdgcn_sched_barrier(0);
    uint2v r0, r1, r2, r3, r4, r5, r6, r7;
    DS_TR(r0, trb, 0);   DS_TR(r1, trb, 512);
    DS_TR(r2, trb, 128); DS_TR(r3, trb, 640);
    DS_TR(r4, trb, 256); DS_TR(r5, trb, 768);
    DS_TR(r6, trb, 384); DS_TR(r7, trb, 896);
    asm volatile("s_waitcnt lgkmcnt(0)" ::: "memory");
    __builtin_amdgcn_sched_barrier(0);
    U4H8 X0, X1, X2, X3;
    X0.u = make_uint4(r0.x, r0.y, r1.x, r1.y);
    X1.u = make_uint4(r2.x, r2.y, r3.x, r3.y);
    X2.u = make_uint4(r4.x, r4.y, r5.x, r5.y);
    X3.u = make_uint4(r6.x, r6.y, r7.x, r7.y);
    acc0 = __builtin_amdgcn_mfma_f32_16x16x32_bf16(X0.h, PB.h, acc0, 0,0,0);
    acc1 = __builtin_amdgcn_mfma_f32_16x16x32_bf16(X1.h, PB.h, acc1, 0,0,0);
    acc2 = __builtin_amdgcn_mfma_f32_16x16x32_bf16(X2.h, PB.h, acc2, 0,0,0);
    acc3 = __builtin_amdgcn_mfma_f32_16x16x32_bf16(X3.h, PB.h, acc3, 0,0,0);

    if (!FUSED) { a00 = n00; a01 = n01; a10 = n10; a11 = n11; }
  }

  lp += __shfl_xor(lp, 16);
  lp += __shfl_xor(lp, 32);

  if (c < NS) {
    if (g == 0) sPart[w][c] = lp;
    #pragma unroll
    for (int r = 0; r < 4; ++r) sPart[w][8 + c*64 +  0 + g*4 + r] = acc0[r];
    #pragma unroll
    for (int r = 0; r < 4; ++r) sPart[w][8 + c*64 + 16 + g*4 + r] = acc1[r];
    #pragma unroll
    for (int r = 0; r < 4; ++r) sPart[w][8 + c*64 + 32 + g*4 + r] = acc2[r];
    #pragma unroll
    for (int r = 0; r < 4; ++r) sPart[w][8 + c*64 + 48 + g*4 + r] = acc3[r];
  }
  if (FUSED) {
    #pragma unroll
    for (int stepi = 0; stepi < 4; ++stepi) {
      const int mask = 1 << stepi;
      #pragma unroll
      for (int dd = 0; dd < 8; ++dd) {
        xs_lo[dd] += __shfl_xor(xs_lo[dd], mask);
        xs_hi[dd] += __shfl_xor(xs_hi[dd], mask);
      }
    }
    if (c == 0) {
      #pragma unroll
      for (int dd = 0; dd < 8; ++dd) {
        sXs[w][g*8 + dd]      = xs_lo[dd];
        sXs[w][g*8 + 32 + dd] = xs_hi[dd];
      }
    }
  }
  __syncthreads();
  float* P = partials_out + (size_t)bid * PARTF2;
  for (int o = t; o < PARTF2; o += 256)
    P[o] = sPart[0][o] + sPart[1][o] + sPart[2][o] + sPart[3][o];
  if (FUSED && t < DIM)
    xsp[(size_t)bid*DIM + t] = sXs[0][t] + sXs[1][t] + sXs[2][t] + sXs[3][t];
}

// ---------------------------------------------------------------------------
// update_slot: one (batch,slot) per 256-thread block (verified R6-R11).
// ---------------------------------------------------------------------------
__device__ __forceinline__ void update_slot(
    int bid, int t,
    const float* __restrict__ partials, const float* __restrict__ xsp,
    const float* __restrict__ prev_base, float* __restrict__ next_base,
    ushort_t* __restrict__ qp_next, float* __restrict__ cb_next,
    int do_qp,
    const float* __restrict__ ln_ff_g, const float* __restrict__ ln_ff_b,
    const float* __restrict__ ln_s_g, const float* __restrict__ ln_s_b,
    const float* __restrict__ Wq, const float* __restrict__ bq,
    const float* __restrict__ Wk, const float* __restrict__ bk,
    const float* __restrict__ Wv, const float* __restrict__ bv,
    const float* __restrict__ W_ih, const float* __restrict__ b_ih,
    const float* __restrict__ W_hh, const float* __restrict__ b_hh,
    const float* __restrict__ W1, const float* __restrict__ b1,
    const float* __restrict__ W2, const float* __restrict__ b2,
    float* ovl)
{
  const int bb = bid >> 3, i = bid & 7;
  const int q4 = t >> 6, d64 = t & 63;
  float* uUX  = ovl;        float* uUpd = ovl+64;   float* uPrev= ovl+128;
  float* uH   = ovl+192;    float* uHln = ovl+256;  float* uFin = ovl+320;
  float* uGx  = ovl+384;    float* uGh  = ovl+576;  float* uM1  = ovl+768;
  float* uS2  = ovl+896;    float* uQ2  = ovl+960;
  float* sRed = ovl+1024;   float* sRed2= ovl+1280;

  const float* Pb = partials + (size_t)bb*BPB*PARTF2;
  const float* xb = xsp + (size_t)bb*BPB*DIM;

  float a = 0.f, xa = 0.f;
  for (int p = q4; p < BPB; p += 4) {
    a  += Pb[p*PARTF2 + 8 + i*DIM + d64];
    xa += xb[p*DIM + d64];
  }
  sRed[q4*64+d64] = a; sRed2[q4*64+d64] = xa;
  if (t < DIM) uPrev[t] = prev_base[((size_t)bb*NS + i)*DIM + t];
  __syncthreads();
  if (t < DIM) {
    float lv = (t < BPB) ? Pb[t*PARTF2 + i] : 0.f;
    #pragma unroll
    for (int m = 1; m < 64; m <<= 1) lv += __shfl_xor(lv, m);
    float acc = sRed[t]+sRed[64+t]+sRed[128+t]+sRed[192+t];
    float xs  = sRed2[t]+sRed2[64+t]+sRed2[128+t]+sRed2[192+t];
    uUX[t] = acc/lv + EPSA*xs;
  }
  __syncthreads();
  {
    const float* wr = Wv + d64*DIM + q4*16;
    const float* ux = uUX + q4*16;
    float s = 0.f;
    #pragma unroll
    for (int d = 0; d < 16; ++d) s = fmaf(ux[d], wr[d], s);
    sRed[q4*64+d64] = s;
  }
  __syncthreads();
  if (t < DIM) uUpd[t] = bv[t]*SUMATTN + sRed[t]+sRed[64+t]+sRed[128+t]+sRed[192+t];
  __syncthreads();
  if (t < 3*DIM) {
    float ax = b_ih[t], ah = b_hh[t];
    const float* wx = W_ih + t*DIM;
    const float* wh = W_hh + t*DIM;
    for (int e = 0; e < DIM; ++e) {
      ax = fmaf(uUpd[e], wx[e], ax);
      ah = fmaf(uPrev[e], wh[e], ah);
    }
    uGx[t] = ax; uGh[t] = ah;
  }
  __syncthreads();
  if (t < DIM) {
    float r = 1.f/(1.f + __expf(-(uGx[t]+uGh[t])));
    float z = 1.f/(1.f + __expf(-(uGx[DIM+t]+uGh[DIM+t])));
    float n = tanhf(uGx[2*DIM+t] + r*uGh[2*DIM+t]);
    float h = (1.f - z)*n + z*uPrev[t];
    uH[t] = h;
    float s1 = h, s2v = h*h;
    #pragma unroll
    for (int m = 1; m < 64; m <<= 1) { s1 += __shfl_xor(s1,m); s2v += __shfl_xor(s2v,m); }
    float mu = s1*(1.f/DIM), var = s2v*(1.f/DIM) - mu*mu;
    float rs = rsqrtf(var + LNEPS);
    uHln[t] = (h - mu)*rs*ln_ff_g[t] + ln_ff_b[t];
  }
  __syncthreads();
  if (t < HID) {
    float s = b1[t];
    const float* wr = W1 + t*DIM;
    for (int d = 0; d < DIM; ++d) s = fmaf(uHln[d], wr[d], s);
    uM1[t] = fmaxf(s, 0.f);
  }
  __syncthreads();
  {
    const float* wr = W2 + d64*HID + q4*32;
    const float* mm = uM1 + q4*32;
    float s = 0.f;
    #pragma unroll
    for (int h = 0; h < 32; ++h) s = fmaf(mm[h], wr[h], s);
    sRed[q4*64+d64] = s;
  }
  __syncthreads();
  if (t < DIM) {
    float fin = uH[t] + b2[t] + sRed[t]+sRed[64+t]+sRed[128+t]+sRed[192+t];
    uFin[t] = fin;
    next_base[((size_t)bb*NS + i)*DIM + t] = fin;
  }
  if (do_qp) {
    __syncthreads();
    if (t < DIM) {
      float v = uFin[t];
      float s1 = v, s2v = v*v;
      #pragma unroll
      for (int m = 1; m < 64; m <<= 1) { s1 += __shfl_xor(s1,m); s2v += __shfl_xor(s2v,m); }
      float mu = s1*(1.f/DIM), var = s2v*(1.f/DIM) - mu*mu;
      float rs = rsqrtf(var + LNEPS);
      uS2[t] = (v - mu)*rs*ln_s_g[t] + ln_s_b[t];
    }
    __syncthreads();
    if (t < DIM) {
      float s = bq[t];
      const float* wr = Wq + t*DIM;
      for (int d = 0; d < DIM; ++d) s = fmaf(uS2[d], wr[d], s);
      uQ2[t] = s;
    }
    __syncthreads();
    if (t < DIM) {
      float s = 0.f;
      for (int e = 0; e < DIM; ++e) s = fmaf(uQ2[e], Wk[e*DIM + t], s);
      qp_next[(size_t)bb*1024 + i*DIM + t] = f2bf(s*SCALE);
      float cv = uQ2[t]*bk[t];
      #pragma unroll
      for (int m = 1; m < 64; m <<= 1) cv += __shfl_xor(cv, m);
      if (t == 0) cb_next[bb*NS + i] = cv*SCALE;
    }
    if (i == 0)
      for (int o = t; o < 512; o += 256) qp_next[(size_t)bb*1024 + 512 + o] = 0;
  }
}

#define SHARED_DECLS \
  __shared__ ushort_t lbuf[NWAVE][2048]; \
  __shared__ float sPart[NWAVE][PARTF2]; \
  __shared__ float sXs[NWAVE][DIM]; \
  __shared__ ushort_t sQp[16*DIM]; \
  __shared__ float sC[NS]; \
  float* ovl = (float*)&lbuf[0][0];

template<int FUSED, int STORE>
__global__ __launch_bounds__(256) void g_flash(
    const float* __restrict__ x, ushort_t* __restrict__ xlnb,
    const float* __restrict__ slots0,
    const ushort_t* __restrict__ qpg, const float* __restrict__ cbg,
    float* __restrict__ partials_out, float* __restrict__ xsp,
    float* __restrict__ dots_out,
    const float* __restrict__ ln_in_g, const float* __restrict__ ln_in_b,
    const float* __restrict__ ln_s_g, const float* __restrict__ ln_s_b,
    const float* __restrict__ Wq, const float* __restrict__ bq,
    const float* __restrict__ Wk, const float* __restrict__ bk)
{
  SHARED_DECLS
  flash_pass<FUSED,STORE>(blockIdx.x, threadIdx.x, x, xlnb, slots0, qpg, cbg,
      partials_out, xsp, dots_out, ln_in_g, ln_in_b, ln_s_g, ln_s_b,
      Wq, bq, Wk, bk, lbuf, sPart, sXs, sQp, sC, ovl);
}

__global__ __launch_bounds__(256) void g_update(
    const float* __restrict__ partials, const float* __restrict__ xsp,
    const float* __restrict__ prev_base, float* __restrict__ next_base,
    ushort_t* __restrict__ qp_next, float* __restrict__ cb_next,
    const float* __restrict__ ln_ff_g, const float* __restrict__ ln_ff_b,
    const float* __restrict__ ln_s_g, const float* __restrict__ ln_s_b,
    const float* __restrict__ Wq, const float* __restrict__ bq,
    const float* __restrict__ Wk, const float* __restrict__ bk,
    const float* __restrict__ Wv, const float* __restrict__ bv,
    const float* __restrict__ W_ih, const float* __restrict__ b_ih,
    const float* __restrict__ W_hh, const float* __restrict__ b_hh,
    const float* __restrict__ W1, const float* __restrict__ b1,
    const float* __restrict__ W2, const float* __restrict__ b2)
{
  __shared__ float ovl2[1600];
  update_slot(blockIdx.x, threadIdx.x, partials, xsp, prev_base, next_base,
              qp_next, cb_next, 1,
              ln_ff_g, ln_ff_b, ln_s_g, ln_s_b, Wq, bq, Wk, bk, Wv, bv,
              W_ih, b_ih, W_hh, b_hh, W1, b1, W2, b2, ovl2);
}

// ---------------------------------------------------------------------------
// k_fin: per-block 1/l; stage this strip's packed bf16 exp-dots into LDS,
// then expand to f32 scaled attn in place (write-once). blk<8 blocks also
// do the final slot update -> outslots.
// ---------------------------------------------------------------------------
__global__ __launch_bounds__(256) void k_fin(
    const float* __restrict__ partials, const float* __restrict__ xsp,
    const float* __restrict__ prev_base,
    float* __restrict__ out, float* __restrict__ outslots,
    const float* __restrict__ ln_ff_g, const float* __restrict__ ln_ff_b,
    const float* __restrict__ ln_s_g, const float* __restrict__ ln_s_b,
    const float* __restrict__ Wq, const float* __restrict__ bq,
    const float* __restrict__ Wk, const float* __restrict__ bk,
    const float* __restrict__ Wv, const float* __restrict__ bv,
    const float* __restrict__ W_ih, const float* __restrict__ b_ih,
    const float* __restrict__ W_hh, const float* __restrict__ b_hh,
    const float* __restrict__ W1, const float* __restrict__ b1,
    const float* __restrict__ W2, const float* __restrict__ b2)
{
  __shared__ float ovl2[1600];
  __shared__ float sLi[NS];
  __shared__ ushort_t sPk[NS*JPB];   // 8 rows x 512 packed bf16 (8 KB)
  const int bid = blockIdx.x, t = threadIdx.x;
  const int b = bid >> 5, blk = bid & 31;
  const float* Pb = partials + (size_t)b*BPB*PARTF2;

  if (t < NS) {
    float ll = 0.f;
    for (int p = 0; p < BPB; ++p) ll += Pb[p*PARTF2 + t];
    sLi[t] = 1.0f/ll;
  }
  // stage bf16 strip to LDS first (reads must precede in-place f32 writes)
  for (int idx = t; idx < NS*JPB/4; idx += 256) {   // 1024 uint2 reads
    int r = idx >> 7, q = idx & 127;                // 128 uint2 per row
    const ushort_t* seg = (const ushort_t*)(out + ((size_t)(b*NS + r))*NTOK + (size_t)blk*JPB);
    *(uint2v*)&sPk[r*JPB + q*4] = *(const uint2v*)(seg + q*4);
  }
  __syncthreads();
  for (int idx = t; idx < 1024; idx += 256) {
    int r = idx >> 7, c4 = idx & 127;
    const ushort_t* pk = &sPk[r*JPB + c4*4];
    float li = sLi[r];
    float4 v;
    v.x = __uint_as_float((unsigned)pk[0] << 16)*li + EPSA;
    v.y = __uint_as_float((unsigned)pk[1] << 16)*li + EPSA;
    v.z = __uint_as_float((unsigned)pk[2] << 16)*li + EPSA;
    v.w = __uint_as_float((unsigned)pk[3] << 16)*li + EPSA;
    *((float4*)out + ((size_t)(b*NS + r))*(NTOK/4) + blk*(JPB/4) + c4) = v;
  }
  if (blk < NS) {
    update_slot(b*NS + blk, t, partials, xsp, prev_base, outslots,
                nullptr, nullptr, 0,
                ln_ff_g, ln_ff_b, ln_s_g, ln_s_b, Wq, bq, Wk, bk, Wv, bv,
                W_ih, b_ih, W_hh, b_hh, W1, b1, W2, b2, ovl2);
  }
}

extern "C" void kernel_launch(void* const* d_in, const int* in_sizes, int n_in,
                              void* d_out, int out_size, void* d_ws, size_t ws_size,
                              hipStream_t stream)
{
  const float* x       = (const float*)d_in[0];
  const float* slots0  = (const float*)d_in[1];
  const float* ln_in_g = (const float*)d_in[2];
  const float* ln_in_b = (const float*)d_in[3];
  const float* ln_s_g  = (const float*)d_in[4];
  const float* ln_s_b  = (const float*)d_in[5];
  const float* ln_ff_g = (const float*)d_in[6];
  const float* ln_ff_b = (const float*)d_in[7];
  const float* Wq = (const float*)d_in[8];
  const float* bq = (const float*)d_in[9];
  const float* Wk = (const float*)d_in[10];
  const float* bk = (const float*)d_in[11];
  const float* Wv = (const float*)d_in[12];
  const float* bv = (const float*)d_in[13];
  const float* W_ih = (const float*)d_in[14];
  const float* b_ih = (const float*)d_in[15];
  const float* W_hh = (const float*)d_in[16];
  const float* b_hh = (const float*)d_in[17];
  const float* W1 = (const float*)d_in[18];
  const float* b1 = (const float*)d_in[19];
  const float* W2 = (const float*)d_in[20];
  const float* b2 = (const float*)d_in[21];

  float* out = (float*)d_out;
  float* outslots = out + (size_t)B*NS*NTOK;

  float* pA   = (float*)d_ws;                          // 1024*520
  float* xsp  = pA + (size_t)GRID*PARTF2;              // 1024*64
  float* cb1  = xsp + (size_t)GRID*DIM;                // 256
  float* cb2  = cb1 + B*NS;                            // 256
  float* s1v  = cb2 + B*NS;                            // 16384
  float* s2v  = s1v + (size_t)B*NS*DIM;                // 16384
  ushort_t* qp1 = (ushort_t*)(s2v + (size_t)B*NS*DIM); // 32*1024 bf16
  ushort_t* qp2 = qp1 + (size_t)B*1024;                // 32*1024 bf16
  ushort_t* xlnb = qp2 + (size_t)B*1024;               // 32*16384*64 bf16

  dim3 gF(GRID), gU(B*NS), blk(256);

  // iter 0: qp0 preamble + fused LN flash (writes xln, xsp, pA)
  g_flash<1,0><<<gF, blk, 0, stream>>>(x, xlnb, slots0, nullptr, nullptr,
      pA, xsp, nullptr, ln_in_g, ln_in_b, ln_s_g, ln_s_b, Wq, bq, Wk, bk);
  // update 0 -> slots1 + qp1
  g_update<<<gU, blk, 0, stream>>>(pA, xsp, slots0, s1v, qp1, cb1,
      ln_ff_g, ln_ff_b, ln_s_g, ln_s_b, Wq, bq, Wk, bk, Wv, bv,
      W_ih, b_ih, W_hh, b_hh, W1, b1, W2, b2);
  // iter 1 flash
  g_flash<0,0><<<gF, blk, 0, stream>>>(nullptr, xlnb, nullptr, qp1, cb1,
      pA, nullptr, nullptr, ln_in_g, ln_in_b, ln_s_g, ln_s_b, Wq, bq, Wk, bk);
  // update 1 -> slots2 + qp2
  g_update<<<gU, blk, 0, stream>>>(pA, xsp, s1v, s2v, qp2, cb2,
      ln_ff_g, ln_ff_b, ln_s_g, ln_s_b, Wq, bq, Wk, bk, Wv, bv,
      W_ih, b_ih, W_hh, b_hh, W1, b1, W2, b2);
  // iter 2 flash: store packed bf16 exp(dots) strip-locally into attn region
  g_flash<0,1><<<gF, blk, 0, stream>>>(nullptr, xlnb, nullptr, qp2, cb2,
      pA, nullptr, out, ln_in_g, ln_in_b, ln_s_g, ln_s_b, Wq, bq, Wk, bk);
  // finalize: expand bf16 -> scaled f32 attn (write once); blk<8 final update
  k_fin<<<gF, blk, 0, stream>>>(pA, xsp, s2v, out, outslots,
      ln_ff_g, ln_ff_b, ln_s_g, ln_s_b, Wq, bq, Wk, bk, Wv, bv,
      W_ih, b_ih, W_hh, b_hh, W1, b1, W2, b2);
}